// Round 5
// baseline (155.349 us; speedup 1.0000x reference)
//
#include <hip/hip_runtime.h>

// SigMMDLoss, fully flattened (derivation in earlier rounds):
//   per-row: A = p[4095]-p[0]; S3 = p[4095] - SP_row/n; S4 = (A^2+S6)/2;
//            S6 = sum d^2; S8 = sum d^3;  time-only features cancel.
// Linear global sums (signed real - gen) in the STREAM kernel:
//   SPall = sum p (all cols), D2 = sum d^2, D3 = sum d^3
// Edge sums (cols 0 & 4095 only) in the tiny EDGE kernel:
//   G1 = sum_rows A, G2 = sum_rows A^2, G3 = sum_rows p[4095]
// Finalize: SP_excl = SPall - G3;
//   FA=G1/B; FS3=(G3 - SP_excl/n)/B; FS4=.5(G2+D2)/B; FS6=D2/B; FS8=D3/B
//   out = sum F^2.
//
// Round-5 change (single variable): ALL stream loads are nontemporal
// (L1-bypass, nt bit) to escape the per-CU L1 miss-tracking limit that
// pins read streams at ~3.1 TB/s regardless of kernel structure.

typedef float vfloat4 __attribute__((ext_vector_type(4)));

constexpr int T_LEN = 4096;
constexpr int B_ROWS = 4096;
constexpr int F4_PER_ARRAY = B_ROWS * T_LEN / 4;      // 4,194,304
constexpr int THREADS_TOTAL = 2 * F4_PER_ARRAY / 4;   // 2,097,152
constexpr int NBLK = THREADS_TOTAL / 256;             // 8192
constexpr int EDGE_BLK = 32;
constexpr int EDGE_OFF = 3 * NBLK;

__global__ __launch_bounds__(256) void sig_stream(const float* __restrict__ real,
                                                  const float* __restrict__ gen,
                                                  double* __restrict__ P) {
  const int tid0 = blockIdx.x * 256 + threadIdx.x;

  vfloat4 a[4];
  float s[4];
  int col4[4];
  // Issue all 8 loads up front (4x float4 + 4x seam scalar), all nontemporal.
#pragma unroll
  for (int i = 0; i < 4; ++i) {
    const float* base = (i < 2) ? real : gen;
    const int f = tid0 + (i & 1) * THREADS_TOTAL;     // float4 index in array
    col4[i] = f & (T_LEN / 4 - 1);                    // 0..1023
    a[i] = __builtin_nontemporal_load(
        reinterpret_cast<const vfloat4*>(base) + f);
    const int sidx = 4 * f + ((col4[i] < 1023) ? 4 : 0);  // clamp at row end
    s[i] = __builtin_nontemporal_load(base + sidx);
  }

  float asp = 0.f, as2 = 0.f, as3 = 0.f;
#pragma unroll
  for (int i = 0; i < 4; ++i) {
    const float sg = (i < 2) ? 1.f : -1.f;
    const float d1 = a[i].y - a[i].x;
    const float d2 = a[i].z - a[i].y;
    const float d3 = a[i].w - a[i].z;
    const float d0 = (col4[i] < 1023) ? (s[i] - a[i].w) : 0.f;  // seam diff
    const float e0 = d0 * d0, e1 = d1 * d1, e2 = d2 * d2, e3 = d3 * d3;
    asp += sg * ((a[i].x + a[i].y) + (a[i].z + a[i].w));
    as2 += sg * ((e0 + e1) + (e2 + e3));
    as3 += sg * ((e0 * d0 + e1 * d1) + (e2 * d2 + e3 * d3));
  }

  // Wave reduce (fp32), then block reduce in LDS (double).
#pragma unroll
  for (int off = 32; off; off >>= 1) {
    asp += __shfl_down(asp, off, 64);
    as2 += __shfl_down(as2, off, 64);
    as3 += __shfl_down(as3, off, 64);
  }
  __shared__ double sred[4][3];
  const int lane = threadIdx.x & 63, wid = threadIdx.x >> 6;
  if (lane == 0) {
    sred[wid][0] = (double)asp;
    sred[wid][1] = (double)as2;
    sred[wid][2] = (double)as3;
  }
  __syncthreads();
  if (threadIdx.x < 3) {
    const double v = sred[0][threadIdx.x] + sred[1][threadIdx.x] +
                     sred[2][threadIdx.x] + sred[3][threadIdx.x];
    P[threadIdx.x * NBLK + blockIdx.x] = v;
  }
}

__global__ __launch_bounds__(256) void sig_edge(const float* __restrict__ real,
                                                const float* __restrict__ gen,
                                                double* __restrict__ P) {
  const int r = blockIdx.x * 256 + threadIdx.x;      // 0..8191
  const int which = r >> 12;
  const int row = r & (B_ROWS - 1);
  const float* p = (which ? gen : real) + (size_t)row * T_LEN;
  const float pf = p[0];
  const float pl = p[T_LEN - 1];
  const double sg = which ? -1.0 : 1.0;
  const double A = (double)pl - (double)pf;
  double g1 = sg * A, g2 = sg * A * A, g3 = sg * (double)pl;

#pragma unroll
  for (int off = 32; off; off >>= 1) {
    g1 += __shfl_down(g1, off, 64);
    g2 += __shfl_down(g2, off, 64);
    g3 += __shfl_down(g3, off, 64);
  }
  __shared__ double sred[4][3];
  const int lane = threadIdx.x & 63, wid = threadIdx.x >> 6;
  if (lane == 0) { sred[wid][0] = g1; sred[wid][1] = g2; sred[wid][2] = g3; }
  __syncthreads();
  if (threadIdx.x < 3) {
    const double v = sred[0][threadIdx.x] + sred[1][threadIdx.x] +
                     sred[2][threadIdx.x] + sred[3][threadIdx.x];
    P[EDGE_OFF + threadIdx.x * EDGE_BLK + blockIdx.x] = v;
  }
}

__global__ __launch_bounds__(256) void sig_final(const double* __restrict__ P,
                                                 float* __restrict__ out) {
  const int tid = threadIdx.x;
  double loc[3] = {0, 0, 0};
  for (int i = tid; i < NBLK; i += 256)
#pragma unroll
    for (int q = 0; q < 3; ++q) loc[q] += P[q * NBLK + i];
  double ge[3] = {0, 0, 0};
  if (tid < EDGE_BLK)
#pragma unroll
    for (int q = 0; q < 3; ++q) ge[q] = P[EDGE_OFF + q * EDGE_BLK + tid];

#pragma unroll
  for (int off = 32; off; off >>= 1)
#pragma unroll
    for (int q = 0; q < 3; ++q) {
      loc[q] += __shfl_down(loc[q], off, 64);
      ge[q] += __shfl_down(ge[q], off, 64);
    }
  __shared__ double sred[4][6];
  const int lane = tid & 63, wid = tid >> 6;
  if (lane == 0)
#pragma unroll
    for (int q = 0; q < 3; ++q) {
      sred[wid][q] = loc[q];
      sred[wid][3 + q] = ge[q];
    }
  __syncthreads();
  if (tid == 0) {
    double Q[6];
#pragma unroll
    for (int q = 0; q < 6; ++q)
      Q[q] = sred[0][q] + sred[1][q] + sred[2][q] + sred[3][q];
    const double SPall = Q[0], D2 = Q[1], D3 = Q[2];
    const double G1 = Q[3], G2 = Q[4], G3 = Q[5];
    const double n = (double)(T_LEN - 1), Bn = (double)B_ROWS;
    const double SPex = SPall - G3;
    const double FA = G1 / Bn;
    const double FS3 = (G3 - SPex / n) / Bn;
    const double FS4 = 0.5 * (G2 + D2) / Bn;
    const double FS6 = D2 / Bn;
    const double FS8 = D3 / Bn;
    out[0] = (float)(FA * FA + FS3 * FS3 + FS4 * FS4 + FS6 * FS6 + FS8 * FS8);
  }
}

extern "C" void kernel_launch(void* const* d_in, const int* in_sizes, int n_in,
                              void* d_out, int out_size, void* d_ws, size_t ws_size,
                              hipStream_t stream) {
  const float* real = (const float*)d_in[0];
  const float* gen = (const float*)d_in[1];
  double* P = (double*)d_ws;   // (3*8192 + 3*32) * 8 = ~197 KB
  float* out = (float*)d_out;

  sig_stream<<<NBLK, 256, 0, stream>>>(real, gen, P);
  sig_edge<<<EDGE_BLK, 256, 0, stream>>>(real, gen, P);
  sig_final<<<1, 256, 0, stream>>>(P, out);
}

// Round 6
// 152.972 us; speedup vs baseline: 1.0155x; 1.0155x over previous
//
#include <hip/hip_runtime.h>

// SigMMDLoss, fully flattened (derivation in earlier rounds):
//   per-row: A = p[4095]-p[0]; S3 = p[4095] - SP_row/n; S4 = (A^2+S6)/2;
//            S6 = sum d^2; S8 = sum d^3;  time-only features cancel.
// Linear global sums (signed real - gen) in the STREAM kernel:
//   SPall = sum p (all cols), D2 = sum d^2, D3 = sum d^3
// Edge sums (cols 0 & 4095 only) in the tiny EDGE kernel:
//   G1 = sum_rows A, G2 = sum_rows A^2, G3 = sum_rows p[4095]
// Finalize: SP_excl = SPall - G3;
//   FA=G1/B; FS3=(G3 - SP_excl/n)/B; FS4=.5(G2+D2)/B; FS6=D2/B; FS8=D3/B
//   out = sum F^2.
//
// Round-6: keep nontemporal loads (L1-bypass beat the per-CU L1 fill-queue
// pin: 43 -> <40 us). NEW: seam elements come from the next lane via
// __shfl_down instead of per-thread scalar reloads -- a wave's 64 float4s
// are consecutive and never straddle a row (1024 % 64 == 0), so only
// lane 63 needs a 4 B load per chunk. Removes ~8 MB redundant traffic and
// 4 vmem instructions/thread (which nt made expensive: no L1 hits).

typedef float vfloat4 __attribute__((ext_vector_type(4)));

constexpr int T_LEN = 4096;
constexpr int B_ROWS = 4096;
constexpr int F4_PER_ARRAY = B_ROWS * T_LEN / 4;      // 4,194,304
constexpr int THREADS_TOTAL = 2 * F4_PER_ARRAY / 4;   // 2,097,152
constexpr int NBLK = THREADS_TOTAL / 256;             // 8192
constexpr int EDGE_BLK = 32;
constexpr int EDGE_OFF = 3 * NBLK;

__global__ __launch_bounds__(256) void sig_stream(const float* __restrict__ real,
                                                  const float* __restrict__ gen,
                                                  double* __restrict__ P) {
  const int tid0 = blockIdx.x * 256 + threadIdx.x;
  const int lane = threadIdx.x & 63;

  vfloat4 a[4];
  float s[4];
  int col4[4];
  // Issue the 4 float4 loads up front (nontemporal).
#pragma unroll
  for (int i = 0; i < 4; ++i) {
    const float* base = (i < 2) ? real : gen;
    const int f = tid0 + (i & 1) * THREADS_TOTAL;     // float4 index in array
    col4[i] = f & (T_LEN / 4 - 1);                    // 0..1023
    a[i] = __builtin_nontemporal_load(
        reinterpret_cast<const vfloat4*>(base) + f);
    // Only the wave's last lane needs the cross-chunk seam element.
    s[i] = 0.f;
    if (lane == 63 && col4[i] < 1023)
      s[i] = __builtin_nontemporal_load(base + 4 * f + 4);
  }

  float asp = 0.f, as2 = 0.f, as3 = 0.f;
#pragma unroll
  for (int i = 0; i < 4; ++i) {
    const float sg = (i < 2) ? 1.f : -1.f;
    // next element for lanes 0..62 = next lane's a.x; lane 63 uses s[i].
    const float nx = __shfl_down(a[i].x, 1, 64);
    const float nxt = (lane == 63) ? s[i] : nx;
    const float d1 = a[i].y - a[i].x;
    const float d2 = a[i].z - a[i].y;
    const float d3 = a[i].w - a[i].z;
    const float d0 = (col4[i] < 1023) ? (nxt - a[i].w) : 0.f;  // seam diff
    const float e0 = d0 * d0, e1 = d1 * d1, e2 = d2 * d2, e3 = d3 * d3;
    asp += sg * ((a[i].x + a[i].y) + (a[i].z + a[i].w));
    as2 += sg * ((e0 + e1) + (e2 + e3));
    as3 += sg * ((e0 * d0 + e1 * d1) + (e2 * d2 + e3 * d3));
  }

  // Wave reduce (fp32), then block reduce in LDS (double).
#pragma unroll
  for (int off = 32; off; off >>= 1) {
    asp += __shfl_down(asp, off, 64);
    as2 += __shfl_down(as2, off, 64);
    as3 += __shfl_down(as3, off, 64);
  }
  __shared__ double sred[4][3];
  const int wid = threadIdx.x >> 6;
  if (lane == 0) {
    sred[wid][0] = (double)asp;
    sred[wid][1] = (double)as2;
    sred[wid][2] = (double)as3;
  }
  __syncthreads();
  if (threadIdx.x < 3) {
    const double v = sred[0][threadIdx.x] + sred[1][threadIdx.x] +
                     sred[2][threadIdx.x] + sred[3][threadIdx.x];
    P[threadIdx.x * NBLK + blockIdx.x] = v;
  }
}

__global__ __launch_bounds__(256) void sig_edge(const float* __restrict__ real,
                                                const float* __restrict__ gen,
                                                double* __restrict__ P) {
  const int r = blockIdx.x * 256 + threadIdx.x;      // 0..8191
  const int which = r >> 12;
  const int row = r & (B_ROWS - 1);
  const float* p = (which ? gen : real) + (size_t)row * T_LEN;
  const float pf = p[0];
  const float pl = p[T_LEN - 1];
  const double sg = which ? -1.0 : 1.0;
  const double A = (double)pl - (double)pf;
  double g1 = sg * A, g2 = sg * A * A, g3 = sg * (double)pl;

#pragma unroll
  for (int off = 32; off; off >>= 1) {
    g1 += __shfl_down(g1, off, 64);
    g2 += __shfl_down(g2, off, 64);
    g3 += __shfl_down(g3, off, 64);
  }
  __shared__ double sred[4][3];
  const int lane = threadIdx.x & 63, wid = threadIdx.x >> 6;
  if (lane == 0) { sred[wid][0] = g1; sred[wid][1] = g2; sred[wid][2] = g3; }
  __syncthreads();
  if (threadIdx.x < 3) {
    const double v = sred[0][threadIdx.x] + sred[1][threadIdx.x] +
                     sred[2][threadIdx.x] + sred[3][threadIdx.x];
    P[EDGE_OFF + threadIdx.x * EDGE_BLK + blockIdx.x] = v;
  }
}

__global__ __launch_bounds__(256) void sig_final(const double* __restrict__ P,
                                                 float* __restrict__ out) {
  const int tid = threadIdx.x;
  double loc[3] = {0, 0, 0};
  for (int i = tid; i < NBLK; i += 256)
#pragma unroll
    for (int q = 0; q < 3; ++q) loc[q] += P[q * NBLK + i];
  double ge[3] = {0, 0, 0};
  if (tid < EDGE_BLK)
#pragma unroll
    for (int q = 0; q < 3; ++q) ge[q] = P[EDGE_OFF + q * EDGE_BLK + tid];

#pragma unroll
  for (int off = 32; off; off >>= 1)
#pragma unroll
    for (int q = 0; q < 3; ++q) {
      loc[q] += __shfl_down(loc[q], off, 64);
      ge[q] += __shfl_down(ge[q], off, 64);
    }
  __shared__ double sred[4][6];
  const int lane = tid & 63, wid = tid >> 6;
  if (lane == 0)
#pragma unroll
    for (int q = 0; q < 3; ++q) {
      sred[wid][q] = loc[q];
      sred[wid][3 + q] = ge[q];
    }
  __syncthreads();
  if (tid == 0) {
    double Q[6];
#pragma unroll
    for (int q = 0; q < 6; ++q)
      Q[q] = sred[0][q] + sred[1][q] + sred[2][q] + sred[3][q];
    const double SPall = Q[0], D2 = Q[1], D3 = Q[2];
    const double G1 = Q[3], G2 = Q[4], G3 = Q[5];
    const double n = (double)(T_LEN - 1), Bn = (double)B_ROWS;
    const double SPex = SPall - G3;
    const double FA = G1 / Bn;
    const double FS3 = (G3 - SPex / n) / Bn;
    const double FS4 = 0.5 * (G2 + D2) / Bn;
    const double FS6 = D2 / Bn;
    const double FS8 = D3 / Bn;
    out[0] = (float)(FA * FA + FS3 * FS3 + FS4 * FS4 + FS6 * FS6 + FS8 * FS8);
  }
}

extern "C" void kernel_launch(void* const* d_in, const int* in_sizes, int n_in,
                              void* d_out, int out_size, void* d_ws, size_t ws_size,
                              hipStream_t stream) {
  const float* real = (const float*)d_in[0];
  const float* gen = (const float*)d_in[1];
  double* P = (double*)d_ws;   // (3*8192 + 3*32) * 8 = ~197 KB
  float* out = (float*)d_out;

  sig_stream<<<NBLK, 256, 0, stream>>>(real, gen, P);
  sig_edge<<<EDGE_BLK, 256, 0, stream>>>(real, gen, P);
  sig_final<<<1, 256, 0, stream>>>(P, out);
}

// Round 7
// 149.456 us; speedup vs baseline: 1.0394x; 1.0235x over previous
//
#include <hip/hip_runtime.h>

// SigMMDLoss, fully flattened (derivation in earlier rounds):
//   per-row: A = p[4095]-p[0]; S3 = p[4095] - SP_row/n; S4 = (A^2+S6)/2;
//            S6 = sum d^2; S8 = sum d^3;  time-only features cancel.
// Linear global sums (signed real - gen) in the STREAM kernel:
//   SPall = sum p (all cols), D2 = sum d^2, D3 = sum d^3
// Edge sums (cols 0 & 4095 only) in the tiny EDGE kernel:
//   G1 = sum_rows A, G2 = sum_rows A^2, G3 = sum_rows p[4095]
// Finalize: SP_excl = SPall - G3;
//   FA=G1/B; FS3=(G3 - SP_excl/n)/B; FS4=.5(G2+D2)/B; FS6=D2/B; FS8=D3/B
//   out = sum F^2.
//
// Round-7: keep nt loads + lane-shuffle seams (r6). Single variable:
// 8 float4 chunks per thread instead of 4 (4096 blocks instead of 8192)
// -> half the reduce tails and block ramp/drain events, 8 independent
// loads in flight per lane. ~50 VGPR, still 8 waves/SIMD.

typedef float vfloat4 __attribute__((ext_vector_type(4)));

constexpr int T_LEN = 4096;
constexpr int B_ROWS = 4096;
constexpr int F4_PER_ARRAY = B_ROWS * T_LEN / 4;      // 4,194,304
constexpr int CHUNKS = 8;                             // float4s per thread
constexpr int STRIPES = CHUNKS / 2;                   // 4 stripes per array
constexpr int THREADS_TOTAL = F4_PER_ARRAY / STRIPES; // 1,048,576
constexpr int NBLK = THREADS_TOTAL / 256;             // 4096
constexpr int EDGE_BLK = 32;
constexpr int EDGE_OFF = 3 * NBLK;

__global__ __launch_bounds__(256) void sig_stream(const float* __restrict__ real,
                                                  const float* __restrict__ gen,
                                                  double* __restrict__ P) {
  const int tid0 = blockIdx.x * 256 + threadIdx.x;
  const int lane = threadIdx.x & 63;

  vfloat4 a[CHUNKS];
  float s[CHUNKS];
  int col4[CHUNKS];
  // Issue all 8 float4 loads up front (nontemporal, independent).
#pragma unroll
  for (int i = 0; i < CHUNKS; ++i) {
    const float* base = (i < STRIPES) ? real : gen;
    const int f = tid0 + (i & (STRIPES - 1)) * THREADS_TOTAL;
    col4[i] = f & (T_LEN / 4 - 1);                    // 0..1023
    a[i] = __builtin_nontemporal_load(
        reinterpret_cast<const vfloat4*>(base) + f);
    // Only the wave's last lane needs the cross-chunk seam element
    // (a wave's 64 float4s are consecutive; 1024 % 64 == 0 -> no row straddle).
    s[i] = 0.f;
    if (lane == 63 && col4[i] < 1023)
      s[i] = __builtin_nontemporal_load(base + 4 * f + 4);
  }

  float asp = 0.f, as2 = 0.f, as3 = 0.f;
#pragma unroll
  for (int i = 0; i < CHUNKS; ++i) {
    const float sg = (i < STRIPES) ? 1.f : -1.f;
    const float nx = __shfl_down(a[i].x, 1, 64);
    const float nxt = (lane == 63) ? s[i] : nx;
    const float d1 = a[i].y - a[i].x;
    const float d2 = a[i].z - a[i].y;
    const float d3 = a[i].w - a[i].z;
    const float d0 = (col4[i] < 1023) ? (nxt - a[i].w) : 0.f;  // seam diff
    const float e0 = d0 * d0, e1 = d1 * d1, e2 = d2 * d2, e3 = d3 * d3;
    asp += sg * ((a[i].x + a[i].y) + (a[i].z + a[i].w));
    as2 += sg * ((e0 + e1) + (e2 + e3));
    as3 += sg * ((e0 * d0 + e1 * d1) + (e2 * d2 + e3 * d3));
  }

  // Wave reduce (fp32), then block reduce in LDS (double).
#pragma unroll
  for (int off = 32; off; off >>= 1) {
    asp += __shfl_down(asp, off, 64);
    as2 += __shfl_down(as2, off, 64);
    as3 += __shfl_down(as3, off, 64);
  }
  __shared__ double sred[4][3];
  const int wid = threadIdx.x >> 6;
  if (lane == 0) {
    sred[wid][0] = (double)asp;
    sred[wid][1] = (double)as2;
    sred[wid][2] = (double)as3;
  }
  __syncthreads();
  if (threadIdx.x < 3) {
    const double v = sred[0][threadIdx.x] + sred[1][threadIdx.x] +
                     sred[2][threadIdx.x] + sred[3][threadIdx.x];
    P[threadIdx.x * NBLK + blockIdx.x] = v;
  }
}

__global__ __launch_bounds__(256) void sig_edge(const float* __restrict__ real,
                                                const float* __restrict__ gen,
                                                double* __restrict__ P) {
  const int r = blockIdx.x * 256 + threadIdx.x;      // 0..8191
  const int which = r >> 12;
  const int row = r & (B_ROWS - 1);
  const float* p = (which ? gen : real) + (size_t)row * T_LEN;
  const float pf = p[0];
  const float pl = p[T_LEN - 1];
  const double sg = which ? -1.0 : 1.0;
  const double A = (double)pl - (double)pf;
  double g1 = sg * A, g2 = sg * A * A, g3 = sg * (double)pl;

#pragma unroll
  for (int off = 32; off; off >>= 1) {
    g1 += __shfl_down(g1, off, 64);
    g2 += __shfl_down(g2, off, 64);
    g3 += __shfl_down(g3, off, 64);
  }
  __shared__ double sred[4][3];
  const int lane = threadIdx.x & 63, wid = threadIdx.x >> 6;
  if (lane == 0) { sred[wid][0] = g1; sred[wid][1] = g2; sred[wid][2] = g3; }
  __syncthreads();
  if (threadIdx.x < 3) {
    const double v = sred[0][threadIdx.x] + sred[1][threadIdx.x] +
                     sred[2][threadIdx.x] + sred[3][threadIdx.x];
    P[EDGE_OFF + threadIdx.x * EDGE_BLK + blockIdx.x] = v;
  }
}

__global__ __launch_bounds__(256) void sig_final(const double* __restrict__ P,
                                                 float* __restrict__ out) {
  const int tid = threadIdx.x;
  double loc[3] = {0, 0, 0};
  for (int i = tid; i < NBLK; i += 256)
#pragma unroll
    for (int q = 0; q < 3; ++q) loc[q] += P[q * NBLK + i];
  double ge[3] = {0, 0, 0};
  if (tid < EDGE_BLK)
#pragma unroll
    for (int q = 0; q < 3; ++q) ge[q] = P[EDGE_OFF + q * EDGE_BLK + tid];

#pragma unroll
  for (int off = 32; off; off >>= 1)
#pragma unroll
    for (int q = 0; q < 3; ++q) {
      loc[q] += __shfl_down(loc[q], off, 64);
      ge[q] += __shfl_down(ge[q], off, 64);
    }
  __shared__ double sred[4][6];
  const int lane = tid & 63, wid = tid >> 6;
  if (lane == 0)
#pragma unroll
    for (int q = 0; q < 3; ++q) {
      sred[wid][q] = loc[q];
      sred[wid][3 + q] = ge[q];
    }
  __syncthreads();
  if (tid == 0) {
    double Q[6];
#pragma unroll
    for (int q = 0; q < 6; ++q)
      Q[q] = sred[0][q] + sred[1][q] + sred[2][q] + sred[3][q];
    const double SPall = Q[0], D2 = Q[1], D3 = Q[2];
    const double G1 = Q[3], G2 = Q[4], G3 = Q[5];
    const double n = (double)(T_LEN - 1), Bn = (double)B_ROWS;
    const double SPex = SPall - G3;
    const double FA = G1 / Bn;
    const double FS3 = (G3 - SPex / n) / Bn;
    const double FS4 = 0.5 * (G2 + D2) / Bn;
    const double FS6 = D2 / Bn;
    const double FS8 = D3 / Bn;
    out[0] = (float)(FA * FA + FS3 * FS3 + FS4 * FS4 + FS6 * FS6 + FS8 * FS8);
  }
}

extern "C" void kernel_launch(void* const* d_in, const int* in_sizes, int n_in,
                              void* d_out, int out_size, void* d_ws, size_t ws_size,
                              hipStream_t stream) {
  const float* real = (const float*)d_in[0];
  const float* gen = (const float*)d_in[1];
  double* P = (double*)d_ws;   // (3*4096 + 3*32) * 8 = ~99 KB
  float* out = (float*)d_out;

  sig_stream<<<NBLK, 256, 0, stream>>>(real, gen, P);
  sig_edge<<<EDGE_BLK, 256, 0, stream>>>(real, gen, P);
  sig_final<<<1, 256, 0, stream>>>(P, out);
}